// Round 4
// baseline (17891.096 us; speedup 1.0000x reference)
//
#include <hip/hip_runtime.h>
#include <hip/hip_bf16.h>

typedef unsigned short ushort_t;
typedef unsigned int u32;
typedef __attribute__((ext_vector_type(8))) short short8;   // 8 x bf16
typedef __attribute__((ext_vector_type(4))) float floatx4;  // MFMA acc / fp32x4

#define Tt 256
#define Hh 512
#define NBLK 128
#define PING_ELEMS 65536u  // 128*512 bf16 per hidden-state buffer

__device__ __forceinline__ float sigf(float x)  { return 1.0f / (1.0f + __expf(-x)); }
__device__ __forceinline__ float tanhf_(float x){ return 1.0f - 2.0f / (__expf(2.0f*x) + 1.0f); }

// fp32 -> bf16, round-to-nearest-even (inputs finite)
__device__ __forceinline__ ushort_t f2bf(float f) {
  u32 u = __float_as_uint(f);
  u += 0x7FFFu + ((u >> 16) & 1u);
  return (ushort_t)(u >> 16);
}

// Hand-rolled grid barrier (sense-reversing). All 128 blocks co-resident
// (16KB LDS, 128 thr, 256 CUs). Release/acquire fences for cross-XCD vis.
__device__ __forceinline__ void gridbar(u32* bar) {
  __syncthreads();
  if (threadIdx.x == 0) {
    __threadfence();  // release: publish this block's h-stores
    u32 gen = __hip_atomic_load(&bar[1], __ATOMIC_ACQUIRE, __HIP_MEMORY_SCOPE_AGENT);
    u32 arr = __hip_atomic_fetch_add(&bar[0], 1u, __ATOMIC_ACQ_REL, __HIP_MEMORY_SCOPE_AGENT);
    if (arr == NBLK - 1u) {
      __hip_atomic_store(&bar[0], 0u, __ATOMIC_RELAXED, __HIP_MEMORY_SCOPE_AGENT);
      __hip_atomic_fetch_add(&bar[1], 1u, __ATOMIC_RELEASE, __HIP_MEMORY_SCOPE_AGENT);
    } else {
      while (__hip_atomic_load(&bar[1], __ATOMIC_ACQUIRE, __HIP_MEMORY_SCOPE_AGENT) == gen)
        __builtin_amdgcn_s_sleep(2);
    }
    __threadfence();  // acquire: invalidate caches before reading remote h
  }
  __syncthreads();
}

// ---------------------------------------------------------------------------
// FP32 inputs / FP32 output; bf16 internally for MFMA.
// 128 blocks x 128 threads (2 waves). block: chain=blk>>5 (d=chain>>1,
// l=chain&1), cb=blk&31 -> hidden units j in [cb*16, cb*16+16).
// MFMA 16x16x32 bf16, A=W^T (register-resident bf16), B=acts (LDS bf16).
// A-frag: A[m=lane&15][k=(lane>>4)*8+j]; B-frag: B[n=lane&15][k=(lane>>4)*8+j];
// C/D: n=lane&15, m=(lane>>4)*4+reg. Gate-row tile mapping: row m of tile mt
// -> gate-col (m&3)*512 + cb*16 + mt*4 + (m>>2), so acc regs r=0..3 are
// i,f,g,o of (b=ln, j=cb*16+mt*4+q): cell math lane-local, c-state in VGPRs
// for the entire 256-step scan. h ping-pongs in ws as bf16 (the MFMA
// quantizes h to bf16 anyway); the fp32 output is written pre-quantization.
// Layer pipeline: iteration it runs layer-0 step it and layer-1 step it-1;
// one grid barrier per iteration (257 total).
// ---------------------------------------------------------------------------
__global__ __launch_bounds__(128, 1) void bilstm_scan(
    const float* __restrict__ x,     // [128][256][512] fp32
    const float* __restrict__ Wx,    // [2][2][512][2048] fp32
    const float* __restrict__ Wh,    // [2][2][512][2048] fp32
    const float* __restrict__ bias,  // [2][2][2048] fp32
    ushort_t* __restrict__ ping,     // [8][128*512] bf16 (zeroed by memset)
    u32* __restrict__ bar,           // barrier words (zeroed by memset)
    float* __restrict__ out)         // [128][256][1024] fp32
{
  __shared__ __align__(16) short actb[2 * 4096];  // 2 slots x (128 rows x 32 k)

  const int blk = blockIdx.x;
  const int chain = blk >> 5, cb = blk & 31;
  const int d = chain >> 1, l = chain & 1;
  const int tid = threadIdx.x;
  const int wv = tid >> 6, lane = tid & 63;
  const int q = lane >> 4, ln = lane & 15;

  // zero LDS: any staging hole yields finite-wrong, never NaN
  for (int i = tid; i < 4096; i += 128) ((u32*)actb)[i] = 0u;
  __syncthreads();

  // ---- W^T into registers (once), fp32 -> bf16. Lane (q,ln), tile mi:
  // A-row ln of tile mt=wv*2+mi -> col=(ln&3)*512 + cb*16 + mt*4 + (ln>>2);
  // k = kc*32 + q*8 + j2.  Each 64B line of W (16 consecutive cols at one k)
  // is consumed entirely by one block -> no chip-wide overfetch.
  short8 wreg[2][32];
  {
    const float* wxb = Wx + (size_t)(l * 2 + d) * 512 * 2048;
    const float* whb = Wh + (size_t)(l * 2 + d) * 512 * 2048;
#pragma unroll
    for (int mi = 0; mi < 2; ++mi) {
      const int m = wv * 2 + mi;
      const int col = (ln & 3) * 512 + cb * 16 + m * 4 + (ln >> 2);
#pragma unroll
      for (int kc = 0; kc < 32; ++kc) {
        union { short8 v; ushort_t u[8]; } tmp;
#pragma unroll
        for (int j2 = 0; j2 < 8; ++j2) {
          const int k = kc * 32 + q * 8 + j2;
          const float wv_ = (k < 512) ? wxb[(size_t)k * 2048 + col]
                                      : whb[(size_t)(k - 512) * 2048 + col];
          tmp.u[j2] = f2bf(wv_);
        }
        wreg[mi][kc] = tmp.v;
      }
    }
  }

  // per-lane biases (fp32): brs[mi][gate] for j = cb*16 + (2wv+mi)*4 + q
  float brs[2][4];
  {
    const float* bp = bias + (size_t)(l * 2 + d) * 2048;
#pragma unroll
    for (int mi = 0; mi < 2; ++mi) {
      const int j = cb * 16 + (wv * 2 + mi) * 4 + q;
#pragma unroll
      for (int r = 0; r < 4; ++r) brs[mi][r] = bp[r * 512 + j];
    }
  }

  float cst[2][8];  // cell state: [mi][batch-tile], register-resident
#pragma unroll
  for (int a = 0; a < 2; ++a)
#pragma unroll
    for (int b2 = 0; b2 < 8; ++b2) cst[a][b2] = 0.f;

  const size_t own_base = (size_t)(l ? 4 : 0) + d * 2;

  for (int it = 0; it <= Tt; ++it) {
    const bool active = (l == 0) ? (it < Tt) : (it >= 1);
    if (active) {
      const int t = (l == 0) ? it : (it - 1);

      // k-concat act sources: k<512 = x (fp32, l=0) or layer-0 h (bf16, l=1);
      // k>=512 = own h[t-1] (bf16).
      const float* xf = nullptr;           // l==0: x at time tx, + row*T*H
      const ushort_t* xh = nullptr;        // l==1: h0[t] ping buffer
      if (l == 0) {
        const int tx = d ? (Tt - 1 - t) : t;
        xf = x + (size_t)tx * Hh;
      } else {
        xh = ping + (size_t)(d * 2 + ((t + 1) & 1)) * PING_ELEMS;
      }
      const ushort_t* hp = ping + (own_base + (t & 1)) * PING_ELEMS;   // own h[t-1]
      ushort_t* hdst = ping + (own_base + ((t + 1) & 1)) * PING_ELEMS; // own h[t]

      floatx4 acc[2][8];
      {
        floatx4 z4 = {0.f, 0.f, 0.f, 0.f};
#pragma unroll
        for (int mi = 0; mi < 2; ++mi)
#pragma unroll
          for (int nt = 0; nt < 8; ++nt) acc[mi][nt] = z4;
      }

      // stage 32-k act chunk kc into slot kc&1. thread: unit u=tid&3 (8 k
      // each), rows (tid>>2)+32*i2. LDS pos rotated: pos=(u+(row>>1))&3.
      auto stage = [&](int kc) {
        const int slot = kc & 1;
        const int k0 = kc * 32;
        const int u = tid & 3;
        const int rb = tid >> 2;
        const int k = k0 + u * 8;
        union { uint4 v; ushort_t us[8]; } pk[4];
        if (l == 0 && k0 < 512) {
          // fp32 x -> bf16
#pragma unroll
          for (int i2 = 0; i2 < 4; ++i2) {
            const int row = rb + 32 * i2;
            const float* src = xf + (size_t)row * ((size_t)Tt * Hh) + k;
            floatx4 f0 = *(const floatx4*)src;
            floatx4 f1 = *(const floatx4*)(src + 4);
#pragma unroll
            for (int e = 0; e < 4; ++e) {
              pk[i2].us[e]     = f2bf(f0[e]);
              pk[i2].us[4 + e] = f2bf(f1[e]);
            }
          }
        } else if (k0 < 512) {
          // layer-0 h (bf16)
#pragma unroll
          for (int i2 = 0; i2 < 4; ++i2) {
            const int row = rb + 32 * i2;
            pk[i2].v = *(const uint4*)(xh + (size_t)row * Hh + k);
          }
        } else {
          // own h[t-1] (bf16)
#pragma unroll
          for (int i2 = 0; i2 < 4; ++i2) {
            const int row = rb + 32 * i2;
            pk[i2].v = *(const uint4*)(hp + (size_t)row * Hh + (k - 512));
          }
        }
#pragma unroll
        for (int i2 = 0; i2 < 4; ++i2) {
          const int row = rb + 32 * i2;
          const int pos = (u + (row >> 1)) & 3;
          *(uint4*)&actb[slot * 4096 + row * 32 + pos * 8] = pk[i2].v;
        }
      };

      stage(0);
#pragma unroll
      for (int kc = 0; kc < 32; ++kc) {
        __syncthreads();   // stage(kc) writes visible; other slot free
        if (kc < 31) stage(kc + 1);
        const int slot = kc & 1;
        const int pos = (q + (ln >> 1)) & 3;  // unit q of row b=nt*16+ln
        short8 af[8];
#pragma unroll
        for (int nt = 0; nt < 8; ++nt) {
          const int b = nt * 16 + ln;
          af[nt] = *(const short8*)&actb[slot * 4096 + b * 32 + pos * 8];
        }
#pragma unroll
        for (int mi = 0; mi < 2; ++mi)
#pragma unroll
          for (int nt = 0; nt < 8; ++nt)
            acc[mi][nt] = __builtin_amdgcn_mfma_f32_16x16x32_bf16(
                wreg[mi][kc], af[nt], acc[mi][nt], 0, 0, 0);
      }

      // LSTM cell: acc[mi][nt][r] = gate r (i,f,g,o) of
      // (b = nt*16+ln, j = cb*16 + (2wv+mi)*4 + q). All lane-local.
      const int tout = d ? (Tt - 1 - t) : t;
#pragma unroll
      for (int mi = 0; mi < 2; ++mi) {
        const int j = cb * 16 + (wv * 2 + mi) * 4 + q;
#pragma unroll
        for (int nt = 0; nt < 8; ++nt) {
          const int b = nt * 16 + ln;
          float iv = sigf  (acc[mi][nt][0] + brs[mi][0]);
          float fv = sigf  (acc[mi][nt][1] + brs[mi][1]);
          float gv = tanhf_(acc[mi][nt][2] + brs[mi][2]);
          float ov = sigf  (acc[mi][nt][3] + brs[mi][3]);
          float cv = fv * cst[mi][nt] + iv * gv;
          cst[mi][nt] = cv;
          float hv = ov * tanhf_(cv);
          hdst[(size_t)b * Hh + j] = f2bf(hv);      // internal state: bf16
          if (l == 1)
            out[((size_t)b * Tt + tout) * 1024 + d * 512 + j] = hv;  // fp32
        }
      }
    }
    gridbar(bar);
  }
}

// ---------------------------------------------------------------------------
extern "C" void kernel_launch(void* const* d_in, const int* in_sizes, int n_in,
                              void* d_out, int out_size, void* d_ws, size_t ws_size,
                              hipStream_t stream) {
  const float* x    = (const float*)d_in[0];  // [128,256,512] fp32
  const float* Wx   = (const float*)d_in[1];  // [2,2,512,2048] fp32
  const float* Wh   = (const float*)d_in[2];  // [2,2,512,2048] fp32
  const float* bias = (const float*)d_in[3];  // [2,2,2048] fp32

  u32* bar = (u32*)d_ws;
  ushort_t* ping = (ushort_t*)((char*)d_ws + 256);

  // zero barrier words + 8 h ping-pong buffers (ws is poisoned each call)
  hipMemsetAsync(d_ws, 0, 256 + (size_t)8 * PING_ELEMS * sizeof(ushort_t), stream);

  hipLaunchKernelGGL(bilstm_scan, dim3(NBLK), dim3(128), 0, stream,
                     x, Wx, Wh, bias, ping, bar, (float*)d_out);
}

// Round 5
// 12497.462 us; speedup vs baseline: 1.4316x; 1.4316x over previous
//
#include <hip/hip_runtime.h>
#include <hip/hip_bf16.h>

typedef unsigned short ushort_t;
typedef unsigned int u32;
typedef unsigned long long u64;
typedef __attribute__((ext_vector_type(8))) short short8;   // 8 x bf16
typedef __attribute__((ext_vector_type(4))) float floatx4;  // MFMA acc / fp32x4

#define Tt 256
#define Hh 512
#define NBLK 128
#define NBAR 64            // blocks per direction-barrier
#define PING_ELEMS 65536u  // 128*512 bf16 per hidden-state buffer
#define KCH 256            // k per staged chunk
#define NCH 4              // 1024 / KCH
#define UROW 32            // 16B units per row (KCH*2B/16B)
#define SLOT_SHORTS (128 * KCH)            // one slot: 128 rows x 256 k bf16
#define SMEM_BYTES (2*SLOT_SHORTS*2 + 128*16*2 + 128*16*4)  // 143360

__device__ __forceinline__ float sigf(float x)  { return 1.0f / (1.0f + __expf(-x)); }
__device__ __forceinline__ float tanhf_(float x){ return 1.0f - 2.0f / (__expf(2.0f*x) + 1.0f); }

// fp32 -> bf16 RNE
__device__ __forceinline__ ushort_t f2bf(float f) {
  u32 u = __float_as_uint(f);
  u += 0x7FFFu + ((u >> 16) & 1u);
  return (ushort_t)(u >> 16);
}

// device-coherence-point accesses for cross-block h traffic (sc1: bypass the
// non-coherent per-XCD L2). No fences / cache maintenance needed anywhere.
__device__ __forceinline__ u64 pload(const ushort_t* p) {
  return __hip_atomic_load((const u64*)p, __ATOMIC_RELAXED, __HIP_MEMORY_SCOPE_AGENT);
}
__device__ __forceinline__ void pstore(ushort_t* p, u64 v) {
  __hip_atomic_store((u64*)p, v, __ATOMIC_RELAXED, __HIP_MEMORY_SCOPE_AGENT);
}

// Relaxed sense-reversing barrier over NBAR blocks (one per direction).
// Release chain: h pstores acked (vmcnt 0) -> arrive RMW at coherence point ->
// releaser bumps gen -> consumer's subsequent pload reads coherence point.
__device__ __forceinline__ void gridbar(u32* bar) {
  __syncthreads();
  if (threadIdx.x == 0) {
    asm volatile("s_waitcnt vmcnt(0)" ::: "memory");  // h-stores at coh. point
    u32 gen = __hip_atomic_load(&bar[1], __ATOMIC_RELAXED, __HIP_MEMORY_SCOPE_AGENT);
    u32 arr = __hip_atomic_fetch_add(&bar[0], 1u, __ATOMIC_RELAXED, __HIP_MEMORY_SCOPE_AGENT);
    if (arr == NBAR - 1u) {
      __hip_atomic_store(&bar[0], 0u, __ATOMIC_RELAXED, __HIP_MEMORY_SCOPE_AGENT);
      asm volatile("s_waitcnt vmcnt(0)" ::: "memory");  // reset before release
      __hip_atomic_fetch_add(&bar[1], 1u, __ATOMIC_RELAXED, __HIP_MEMORY_SCOPE_AGENT);
    } else {
      while (__hip_atomic_load(&bar[1], __ATOMIC_RELAXED, __HIP_MEMORY_SCOPE_AGENT) == gen)
        __builtin_amdgcn_s_sleep(1);
    }
    asm volatile("" ::: "memory");
  }
  __syncthreads();
}

// ---------------------------------------------------------------------------
// Structure as round 4 (register W^T, lane-local gates, register c-state,
// layer-pipelined 257 intervals), with: relaxed coherence-point barrier
// (per direction), sc1 h ping-pong, 4x256-k double-buffered LDS chunks
// (2x64 KB dynamic), repacked h/out stores.
// ---------------------------------------------------------------------------
__global__ __launch_bounds__(128, 1) void bilstm_scan(
    const float* __restrict__ x,     // [128][256][512] fp32
    const float* __restrict__ Wx,    // [2][2][512][2048] fp32
    const float* __restrict__ Wh,    // [2][2][512][2048] fp32
    const float* __restrict__ bias,  // [2][2][2048] fp32
    ushort_t* __restrict__ ping,     // [8][128*512] bf16 (zeroed by memset)
    u32* __restrict__ barws,         // barrier words (zeroed by memset)
    float* __restrict__ out)         // [128][256][1024] fp32
{
  extern __shared__ __align__(16) char smem[];
  short* actb = (short*)smem;                                   // 2 x 64 KB
  ushort_t* hrep = (ushort_t*)(smem + 2 * SLOT_SHORTS * 2);     // 128x16 bf16
  float* hrep32 = (float*)(smem + 2 * SLOT_SHORTS * 2 + 4096);  // 128x16 f32

  const int blk = blockIdx.x;
  const int chain = blk >> 5, cb = blk & 31;
  const int d = chain >> 1, l = chain & 1;
  const int tid = threadIdx.x;
  const int wv = tid >> 6, lane = tid & 63;
  const int q = lane >> 4, ln = lane & 15;
  u32* bar = barws + d * 16;  // per-direction barrier, 64 B apart

  // zero LDS (staging holes -> finite-wrong, never NaN)
  for (int i = tid; i < (int)(SMEM_BYTES / 4); i += 128) ((u32*)smem)[i] = 0u;
  __syncthreads();

  // ---- W^T into registers (once), fp32 -> bf16. A-row ln of tile
  // mt=wv*2+mi -> gate-col (ln&3)*512 + cb*16 + mt*4 + (ln>>2); k=kc*32+q*8+j.
  short8 wreg[2][32];
  {
    const float* wxb = Wx + (size_t)(l * 2 + d) * 512 * 2048;
    const float* whb = Wh + (size_t)(l * 2 + d) * 512 * 2048;
#pragma unroll
    for (int mi = 0; mi < 2; ++mi) {
      const int m = wv * 2 + mi;
      const int col = (ln & 3) * 512 + cb * 16 + m * 4 + (ln >> 2);
#pragma unroll
      for (int kc = 0; kc < 32; ++kc) {
        union { short8 v; ushort_t u[8]; } tmp;
#pragma unroll
        for (int j2 = 0; j2 < 8; ++j2) {
          const int k = kc * 32 + q * 8 + j2;
          const float wv_ = (k < 512) ? wxb[(size_t)k * 2048 + col]
                                      : whb[(size_t)(k - 512) * 2048 + col];
          tmp.u[j2] = f2bf(wv_);
        }
        wreg[mi][kc] = tmp.v;
      }
    }
  }

  float brs[2][4];
  {
    const float* bp = bias + (size_t)(l * 2 + d) * 2048;
#pragma unroll
    for (int mi = 0; mi < 2; ++mi) {
      const int j = cb * 16 + (wv * 2 + mi) * 4 + q;
#pragma unroll
      for (int r = 0; r < 4; ++r) brs[mi][r] = bp[r * 512 + j];
    }
  }

  float cst[2][8];
#pragma unroll
  for (int a = 0; a < 2; ++a)
#pragma unroll
    for (int b2 = 0; b2 < 8; ++b2) cst[a][b2] = 0.f;

  const size_t own_base = (size_t)(l ? 4 : 0) + d * 2;

  for (int it = 0; it <= Tt; ++it) {
    const bool active = (l == 0) ? (it < Tt) : (it >= 1);
    if (active) {
      const int t = (l == 0) ? it : (it - 1);

      const float* xf = nullptr;     // l==0: x at time tx
      const ushort_t* xh = nullptr;  // l==1: h0[t]
      if (l == 0) {
        const int tx = d ? (Tt - 1 - t) : t;
        xf = x + (size_t)tx * Hh;
      } else {
        xh = ping + (size_t)(d * 2 + ((t + 1) & 1)) * PING_ELEMS;
      }
      const ushort_t* hp = ping + (own_base + (t & 1)) * PING_ELEMS;   // own h[t-1]
      ushort_t* hdst = ping + (own_base + ((t + 1) & 1)) * PING_ELEMS; // own h[t]

      floatx4 acc[2][8];
      {
        floatx4 z4 = {0.f, 0.f, 0.f, 0.f};
#pragma unroll
        for (int mi = 0; mi < 2; ++mi)
#pragma unroll
          for (int nt = 0; nt < 8; ++nt) acc[mi][nt] = z4;
      }

      // stage 256-k chunk kc into slot kc&1. Thread = row (batch). Unit u
      // (16B) stored at pos=(u+rot)&31, rot=(row>>1)&31 -> both ds_write_b128
      // and ds_read_b128 are 8 lanes per 4-bank group (b128 minimum).
      auto stage = [&](int kc) {
        short* dst = actb + (kc & 1) * SLOT_SHORTS;
        const int r = tid;
        const int rot = (r >> 1) & 31;
        const int k0 = kc * KCH;
        if (l == 0 && kc < 2) {
          const float* src = xf + (size_t)r * ((size_t)Tt * Hh) + k0;
#pragma unroll 4
          for (int u = 0; u < UROW; ++u) {
            floatx4 f0 = *(const floatx4*)(src + u * 8);
            floatx4 f1 = *(const floatx4*)(src + u * 8 + 4);
            union { uint4 v; ushort_t us[8]; } pk;
#pragma unroll
            for (int e = 0; e < 4; ++e) {
              pk.us[e] = f2bf(f0[e]);
              pk.us[4 + e] = f2bf(f1[e]);
            }
            const int pos = (u + rot) & 31;
            *(uint4*)&dst[r * KCH + pos * 8] = pk.v;
          }
        } else {
          const ushort_t* src = (kc < 2) ? (xh + (size_t)r * Hh + k0)
                                         : (hp + (size_t)r * Hh + (k0 - 512));
#pragma unroll 4
          for (int u = 0; u < UROW; ++u) {
            u64 a = pload(src + u * 8);
            u64 b = pload(src + u * 8 + 4);
            uint4 v;
            v.x = (u32)a; v.y = (u32)(a >> 32);
            v.z = (u32)b; v.w = (u32)(b >> 32);
            const int pos = (u + rot) & 31;
            *(uint4*)&dst[r * KCH + pos * 8] = v;
          }
        }
      };

      auto compute = [&](int kc) {
        const short* src = actb + (kc & 1) * SLOT_SHORTS;
#pragma unroll
        for (int s = 0; s < 8; ++s) {
          short8 af[8];
#pragma unroll
          for (int nt = 0; nt < 8; ++nt) {
            const int b = nt * 16 + ln;
            const int pos = (s * 4 + q + ((b >> 1) & 31)) & 31;
            af[nt] = *(const short8*)&src[b * KCH + pos * 8];
          }
          const int kidx = kc * 8 + s;
#pragma unroll
          for (int mi = 0; mi < 2; ++mi)
#pragma unroll
            for (int nt = 0; nt < 8; ++nt)
              acc[mi][nt] = __builtin_amdgcn_mfma_f32_16x16x32_bf16(
                  wreg[mi][kidx], af[nt], acc[mi][nt], 0, 0, 0);
        }
      };

      stage(0);
#pragma unroll
      for (int kc = 0; kc < NCH; ++kc) {
        __syncthreads();          // chunk kc staged; other slot free
        if (kc < NCH - 1) stage(kc + 1);
        compute(kc);
      }

      // cell math (lane-local), repack h via LDS for contiguous stores
      const int tout = d ? (Tt - 1 - t) : t;
#pragma unroll
      for (int mi = 0; mi < 2; ++mi) {
        const int jj = (wv * 2 + mi) * 4 + q;
#pragma unroll
        for (int nt = 0; nt < 8; ++nt) {
          const int b = nt * 16 + ln;
          float iv = sigf  (acc[mi][nt][0] + brs[mi][0]);
          float fv = sigf  (acc[mi][nt][1] + brs[mi][1]);
          float gv = tanhf_(acc[mi][nt][2] + brs[mi][2]);
          float ov = sigf  (acc[mi][nt][3] + brs[mi][3]);
          float cv = fv * cst[mi][nt] + iv * gv;
          cst[mi][nt] = cv;
          float hv = ov * tanhf_(cv);
          hrep[b * 16 + jj] = f2bf(hv);
          if (l == 1) hrep32[b * 16 + jj] = hv;
        }
      }
      __syncthreads();
      {
        const int r = tid;  // row = batch
        uint4 h0v = *(uint4*)&hrep[r * 16];
        uint4 h1v = *(uint4*)&hrep[r * 16 + 8];
        ushort_t* dp = hdst + (size_t)r * Hh + cb * 16;
        pstore(dp,      ((u64)h0v.y << 32) | h0v.x);
        pstore(dp + 4,  ((u64)h0v.w << 32) | h0v.z);
        pstore(dp + 8,  ((u64)h1v.y << 32) | h1v.x);
        pstore(dp + 12, ((u64)h1v.w << 32) | h1v.z);
        if (l == 1) {
          float* op = out + ((size_t)r * Tt + tout) * 1024 + d * 512 + cb * 16;
#pragma unroll
          for (int u = 0; u < 4; ++u)
            *(floatx4*)(op + u * 4) = *(floatx4*)&hrep32[r * 16 + u * 4];
        }
      }
    }
    gridbar(bar);
  }
}

// ---------------------------------------------------------------------------
extern "C" void kernel_launch(void* const* d_in, const int* in_sizes, int n_in,
                              void* d_out, int out_size, void* d_ws, size_t ws_size,
                              hipStream_t stream) {
  const float* x    = (const float*)d_in[0];  // [128,256,512] fp32
  const float* Wx   = (const float*)d_in[1];  // [2,2,512,2048] fp32
  const float* Wh   = (const float*)d_in[2];  // [2,2,512,2048] fp32
  const float* bias = (const float*)d_in[3];  // [2,2,2048] fp32

  u32* bar = (u32*)d_ws;
  ushort_t* ping = (ushort_t*)((char*)d_ws + 256);

  hipFuncSetAttribute((const void*)bilstm_scan,
                      hipFuncAttributeMaxDynamicSharedMemorySize, SMEM_BYTES);

  // zero barrier words + 8 h ping-pong buffers (ws is poisoned each call)
  hipMemsetAsync(d_ws, 0, 256 + (size_t)8 * PING_ELEMS * sizeof(ushort_t), stream);

  hipLaunchKernelGGL(bilstm_scan, dim3(NBLK), dim3(128), SMEM_BYTES, stream,
                     x, Wx, Wh, bias, ping, bar, (float*)d_out);
}